// Round 6
// baseline (638.192 us; speedup 1.0000x reference)
//
#include <hip/hip_runtime.h>
#include <math.h>

// ---------------- problem constants ----------------
static constexpr int CCH = 180;
static constexpr float SCALE_Q = 0.18257418583505536f; // 30^-0.5

typedef short short8 __attribute__((ext_vector_type(8)));
typedef float f32x4 __attribute__((ext_vector_type(4)));

// ---------------- ws layout (float offsets) ----------------
static constexpr size_t OFF_ATTNB = 0;         // bf16 32768x192
static constexpr size_t OFF_XNP   = 3145728;   // bf16 2x18x34x34x192 (3,995,136 f)
static constexpr size_t OFF_Y1P   = 7140864;   // bf16 2x18x34x34x64 (1,331,712 f)
static constexpr size_t OFF_QKVB  = 8472576;   // bf16 q,k:[384][512][32]x2, v:[384][32][512]
static constexpr size_t OFF_HID   = 0;         // bf16 32768x768 (12,582,912 f) aliases dead bufs
static constexpr size_t OFF_Y2B   = 17909760;  // bf16 32768x192
static constexpr size_t OFF_X2    = 21055488;  // f32 32768x180
static constexpr size_t OFF_X2N   = 26953728;  // bf16 32768x192
static constexpr size_t OFF_BIASB = 30099456;  // bf16 6x512x512
static constexpr size_t OFF_WQKV  = 30885888;  // bf16 640x192
static constexpr size_t OFF_WPROJ = 30947328;  // bf16 256x192
static constexpr size_t OFF_WFC1  = 30971904;  // bf16 768x192
static constexpr size_t OFF_WFC2  = 31045632;  // bf16 256x768
static constexpr size_t OFF_WB1   = 31143936;  // bf16 27x64x192
static constexpr size_t OFF_WB2   = 31309824;  // bf16 27x192x64
static constexpr size_t OFF_PPART = 31475712;  // f32 64x180
static constexpr size_t OFF_POOL  = 31487232;  // 360
static constexpr size_t OFF_AM    = 31487592;  // 360 -> end ~126 MiB

__device__ __forceinline__ float geluf(float v){
  return 0.5f*v*(1.0f + erff(v*0.70710678118654752440f));
}
__device__ __forceinline__ short f2bf(float f){
  unsigned u = __float_as_uint(f);
  unsigned r = (u + 0x7FFFu + ((u>>16)&1u)) >> 16;
  return (short)r;
}
__device__ __forceinline__ float bf2f(short s){
  return __uint_as_float(((unsigned)(unsigned short)s)<<16);
}
__device__ __forceinline__ void gload16(const void* g, void* l){
  __builtin_amdgcn_global_load_lds(
    (const __attribute__((address_space(1))) unsigned int*)g,
    (__attribute__((address_space(3))) unsigned int*)l, 16, 0, 0);
}

// ---------------- gemm weights -> padded bf16 ----------------
__global__ void prep_wb(const float* __restrict__ qkv_w, const float* __restrict__ proj_w,
                        const float* __restrict__ fc1_w, const float* __restrict__ fc2_w,
                        short* __restrict__ wq, short* __restrict__ wp,
                        short* __restrict__ w1, short* __restrict__ w2){
  int i = blockIdx.x*256 + threadIdx.x;
  if(i < 122880){
    int o = i/192, k = i - o*192;
    wq[i] = (o<540 && k<180) ? f2bf(qkv_w[o*180+k]) : (short)0;
  } else if(i < 172032){
    int j = i-122880; int o = j/192, k = j - o*192;
    wp[j] = (o<180 && k<180) ? f2bf(proj_w[o*180+k]) : (short)0;
  } else if(i < 319488){
    int j = i-172032; int o = j/192, k = j - o*192;
    w1[j] = (o<720 && k<180) ? f2bf(fc1_w[o*180+k]) : (short)0;
  } else if(i < 516096){
    int j = i-319488; int o = j/768, k = j - o*768;
    w2[j] = (o<180 && k<720) ? f2bf(fc2_w[o*720+k]) : (short)0;
  }
}

// ---------------- conv weights -> bf16 [tap][co][ci] padded ----------------
__global__ void prep_wbc(const float* __restrict__ cw1, const float* __restrict__ cw2,
                         short* __restrict__ wb1, short* __restrict__ wb2){
  int i = blockIdx.x*256 + threadIdx.x;
  if(i < 27*64*192){
    int t = i/(64*192); int rem = i - t*64*192;
    int co = rem/192, ci = rem - co*192;
    wb1[i] = (co<60 && ci<180) ? f2bf(cw1[(co*180+ci)*27 + t]) : (short)0;
    int co2 = rem/64, ci2 = rem - co2*64;
    wb2[i] = (co2<180 && ci2<60) ? f2bf(cw2[(co2*60+ci2)*27 + t]) : (short)0;
  }
}

// ---------------- bias table -> packed bf16 pairs ----------------
__global__ __launch_bounds__(256) void bias_prep(const int* __restrict__ rpi,
    const float* __restrict__ rpb, short* __restrict__ biasB){
  int i = blockIdx.x*256 + threadIdx.x;   // q*512+k
  int q = i>>9, k = i&511;
  int kt = k>>5, kin = k&31;
  int j = kt*32 + ((kin<16) ? 2*kin : 2*(kin-16)+1);
  int idx = rpi[i];
  #pragma unroll
  for(int h=0;h<6;h++)
    biasB[((size_t)h*512 + q)*512 + j] = f2bf(rpb[idx*6+h]);
}

// ---------------- layernorm -> bf16 (padded xnp or compact 192) ----------------
template<int PADDED>
__global__ __launch_bounds__(256) void ln_bf16(const float* __restrict__ x,
    const float* __restrict__ g, const float* __restrict__ b, short* __restrict__ outb){
  int token = blockIdx.x*4 + (threadIdx.x>>6);
  int lane  = threadIdx.x & 63;
  const float* row = x + (size_t)token*CCH;
  float v0 = row[lane], v1 = row[lane+64];
  float v2 = (lane<52) ? row[lane+128] : 0.f;
  float s = v0+v1+v2;
  #pragma unroll
  for(int m=1;m<64;m<<=1) s += __shfl_xor(s, m, 64);
  float mean = s*(1.f/180.f);
  float d0=v0-mean, d1=v1-mean, d2=(lane<52)?(v2-mean):0.f;
  float sq = d0*d0+d1*d1+d2*d2;
  #pragma unroll
  for(int m=1;m<64;m<<=1) sq += __shfl_xor(sq, m, 64);
  float rstd = rsqrtf(sq*(1.f/180.f)+1e-5f);
  size_t orow;
  if(PADDED){
    int bb=token>>14, d=(token>>10)&15, h=(token>>5)&31, w=token&31;
    orow = ((size_t)((bb*18+d+1)*34 + h+1)*34 + w+1)*192;
  } else {
    orow = (size_t)token*192;
  }
  short* o = outb + orow;
  o[lane]    = f2bf(d0*rstd*g[lane]    + b[lane]);
  o[lane+64] = f2bf(d1*rstd*g[lane+64] + b[lane+64]);
  o[lane+128]= (lane<52) ? f2bf(d2*rstd*g[lane+128] + b[lane+128]) : (short)0;
}

// ---------------- conv1: 192->64, padded input, gload_lds dbuf ----------------
__global__ __launch_bounds__(256,2) void conv1_mfma(const short* __restrict__ in,
    const short* __restrict__ wb, const float* __restrict__ cbias, short* __restrict__ y1p){
  __shared__ short lds[2][19584];   // 3 rows x 34 w x 192 ci, XOR-swizzled
  int bid = blockIdx.x;
  int xcd = bid&7, idx = bid>>3;
  int b = idx>>6, dd=(idx>>5)&1, h=idx&31;
  int d = xcd*2+dd;
  int tid=threadIdx.x, l=tid&63, l15=l&15, g=l>>4, wid=tid>>6;
  int soff[10];
  #pragma unroll
  for(int it=0; it<10; it++){
    int i = it*256 + tid;
    int rr = i/24, s = i - rr*24;
    soff[it] = rr*192 + (((s&~7)|((s&7)^(rr&7)))<<3);
  }
  f32x4 acc[2];
  acc[0]=(f32x4){0.f,0.f,0.f,0.f}; acc[1]=(f32x4){0.f,0.f,0.f,0.f};
  auto STAGE=[&](int kd,int p){
    const short* S = in + ((size_t)((b*18+d+kd)*34 + h)*34)*192;
    #pragma unroll
    for(int it=0; it<10; it++){
      if(it<9 || tid<144)
        gload16(S + soff[it], &lds[p][(it*256 + wid*64)*8]);
    }
  };
  STAGE(0,0);
  __syncthreads();
  for(int kd=0;kd<3;kd++){
    if(kd<2) STAGE(kd+1,(kd+1)&1);
    const short* buf = lds[kd&1];
    #pragma unroll
    for(int kh=0;kh<3;kh++)
    #pragma unroll
    for(int kw=0;kw<3;kw++){
      const short* wt = wb + (size_t)((kd*3+kh)*3+kw)*12288 + (wid*16+l15)*192;
      int rr0 = kh*34+kw+l15, rr1 = rr0+16;
      #pragma unroll
      for(int ks=0;ks<6;ks++){
        int s = ks*4+g;
        short8 a0 = *(const short8*)&buf[rr0*192 + (((s&~7)|((s&7)^(rr0&7)))<<3)];
        short8 a1 = *(const short8*)&buf[rr1*192 + (((s&~7)|((s&7)^(rr1&7)))<<3)];
        short8 bv = *(const short8*)&wt[ks*32 + g*8];
        acc[0] = __builtin_amdgcn_mfma_f32_16x16x32_bf16(a0, bv, acc[0],0,0,0);
        acc[1] = __builtin_amdgcn_mfma_f32_16x16x32_bf16(a1, bv, acc[1],0,0,0);
      }
    }
    __syncthreads();
  }
  int co = wid*16+l15;
  float bb = (co<60)? cbias[co] : 0.f;
  size_t row0 = ((size_t)(b*18+d+1)*34 + h+1)*34 + 1;
  #pragma unroll
  for(int mi=0;mi<2;mi++)
    #pragma unroll
    for(int reg=0;reg<4;reg++){
      int r = mi*16 + g*4 + reg;
      y1p[(row0 + r)*64 + co] = f2bf(geluf(acc[mi][reg] + bb));
    }
}

// ---------------- conv2: 64->192, padded input, gload_lds dbuf ----------------
__global__ __launch_bounds__(256,4) void conv2_mfma(const short* __restrict__ in,
    const short* __restrict__ wb, const float* __restrict__ cbias, short* __restrict__ y2b){
  __shared__ short lds[2][6528];   // 3 rows x 34 w x 64 ci
  int bid = blockIdx.x;
  int xcd = bid&7, idx = bid>>3;
  int b = idx>>6, dd=(idx>>5)&1, h=idx&31;
  int d = xcd*2+dd;
  int tid=threadIdx.x, l=tid&63, l15=l&15, g=l>>4, wid=tid>>6;
  int soff[4];
  #pragma unroll
  for(int it=0; it<4; it++){
    int i = it*256 + tid;
    int rr = i>>3, s = i&7;
    soff[it] = rr*64 + ((s^(rr&7))<<3);
  }
  f32x4 acc[2][3];
  #pragma unroll
  for(int mi=0;mi<2;mi++)
    #pragma unroll
    for(int nj=0;nj<3;nj++) acc[mi][nj]=(f32x4){0.f,0.f,0.f,0.f};
  auto STAGE=[&](int kd,int p){
    const short* S = in + ((size_t)((b*18+d+kd)*34 + h)*34)*64;
    #pragma unroll
    for(int it=0; it<4; it++){
      if(it<3 || tid<48)
        gload16(S + soff[it], &lds[p][(it*256 + wid*64)*8]);
    }
  };
  STAGE(0,0);
  __syncthreads();
  for(int kd=0;kd<3;kd++){
    if(kd<2) STAGE(kd+1,(kd+1)&1);
    const short* buf = lds[kd&1];
    #pragma unroll
    for(int kh=0;kh<3;kh++)
    #pragma unroll
    for(int kw=0;kw<3;kw++){
      const short* wt = wb + (size_t)((kd*3+kh)*3+kw)*12288;
      int rr0 = kh*34+kw+l15, rr1 = rr0+16;
      #pragma unroll
      for(int ks=0;ks<2;ks++){
        int s = ks*4+g;
        short8 a0 = *(const short8*)&buf[rr0*64 + ((s^(rr0&7))<<3)];
        short8 a1 = *(const short8*)&buf[rr1*64 + ((s^(rr1&7))<<3)];
        short8 bv[3];
        #pragma unroll
        for(int nj=0;nj<3;nj++)
          bv[nj] = *(const short8*)&wt[(size_t)(wid*48+nj*16+l15)*64 + ks*32 + g*8];
        #pragma unroll
        for(int nj=0;nj<3;nj++){
          acc[0][nj] = __builtin_amdgcn_mfma_f32_16x16x32_bf16(a0, bv[nj], acc[0][nj],0,0,0);
          acc[1][nj] = __builtin_amdgcn_mfma_f32_16x16x32_bf16(a1, bv[nj], acc[1][nj],0,0,0);
        }
      }
    }
    __syncthreads();
  }
  size_t token0 = ((size_t)(b*16+d)*32 + h)*32;
  #pragma unroll
  for(int mi=0;mi<2;mi++)
    #pragma unroll
    for(int nj=0;nj<3;nj++){
      int co = wid*48 + nj*16 + l15;
      if(co<180){
        float bb = cbias[co];
        #pragma unroll
        for(int reg=0;reg<4;reg++){
          int r = mi*16 + g*4 + reg;
          y2b[(token0 + r)*192 + co] = f2bf(acc[mi][nj][reg] + bb);
        }
      }
    }
}

// ---------------- pool (2-stage) ----------------
__global__ __launch_bounds__(192) void pool1_kernel(const short* __restrict__ y2b,
                                                    float* __restrict__ part){
  int b = blockIdx.x>>5, chunk = blockIdx.x&31;
  int c = threadIdx.x;
  if(c<180){
    float s = 0.f;
    const short* base = y2b + ((size_t)b*16384 + chunk*512)*192 + c;
    for(int it=0;it<512;it++) s += bf2f(base[(size_t)it*192]);
    part[blockIdx.x*180 + c] = s;
  }
}
__global__ void pool2_kernel(const float* __restrict__ part, float* __restrict__ pooled){
  int i = blockIdx.x*256 + threadIdx.x;
  if(i<360){
    int b = i/180, c = i - b*180;
    float s = 0.f;
    for(int ch=0;ch<32;ch++) s += part[(b*32+ch)*180 + c];
    pooled[i] = s*(1.f/16384.f);
  }
}

// ---------------- channel attention (tiny) ----------------
__global__ void chattn_kernel(const float* __restrict__ pooled,
    const float* __restrict__ caw1, const float* __restrict__ cab1,
    const float* __restrict__ caw2, const float* __restrict__ cab2,
    float* __restrict__ amask){
  __shared__ float hid[2][6];
  int t = threadIdx.x;
  if(t<12){
    int b = t/6, qh = t - b*6;
    float s = cab1[qh];
    for(int c=0;c<180;c++) s += pooled[b*180+c]*caw1[qh*180+c];
    hid[b][qh] = fmaxf(s, 0.f);
  }
  __syncthreads();
  for(int i=t;i<360;i+=64){
    int b = i/180, c = i - b*180;
    float s = cab2[c];
    #pragma unroll
    for(int qh=0;qh<6;qh++) s += hid[b][qh]*caw2[c*6+qh];
    amask[i] = 1.f/(1.f+__expf(-s));
  }
}

// ---------------- window-token <-> row mappings ----------------
__device__ __forceinline__ void wtok_decomp(int t, int& b, int& dd, int& hh, int& ww){
  int win = t >> 9, n = t & 511;
  int sb = win >> 2, wi = win & 3;
  int wh = wi >> 1, wwi = wi & 1;
  b = sb >> 3; int r = sb & 7;
  int id = r >> 2, ih = (r>>1)&1, iw = r&1;
  int td = n >> 6, th = (n>>3)&7, tw = n & 7;
  dd = td*2 + id;
  hh = (wh*8+th)*2 + ih;
  ww = (wwi*8+tw)*2 + iw;
}
__device__ __forceinline__ int wtok_to_row(int t){
  int b,dd,hh,ww; wtok_decomp(t,b,dd,hh,ww);
  return b*16384 + (dd*32+hh)*32 + ww;
}
__device__ __forceinline__ int wtok_to_prow(int t){
  int b,dd,hh,ww; wtok_decomp(t,b,dd,hh,ww);
  return ((b*18+dd+1)*34 + hh+1)*34 + ww + 1;
}

// ---------------- bf16 MFMA GEMM 128x128, gload_lds dbuf pipeline ----------------
// MODE 0: qkv (A=xnp padded-gathered; q/k head-major + pad-zeroing, v transposed)
// MODE 1: proj (A=attnb; out x2 = v + x + y2b*am*0.01)
// MODE 2: fc1 (A=x2n; gelu -> hid bf16 [t][768])
// MODE 3: fc2 (A=hid; v + x2 -> d_out f32)
template<int MODE, int NOUT, int KTOT>
__global__ __launch_bounds__(256) void mgemm(const short* __restrict__ A,
    const short* __restrict__ Wb, const float* __restrict__ bias, void* __restrict__ outv,
    const float* __restrict__ e0, const float* __restrict__ e1,
    const float* __restrict__ e2){
  __shared__ short As[2][8192];
  __shared__ short Bs[2][8192];
  __shared__ int rowmap[128];
  int lin = blockIdx.y*gridDim.x + blockIdx.x;
  int xcd = lin&7, k = lin>>3;
  int bm = xcd*32 + (k & 31);
  int bn = k >> 5;
  int tid = threadIdx.x;
  int l = tid&63, l15=l&15, g=l>>4, wid=tid>>6;
  int wm = wid>>1, wn = wid&1;
  constexpr int RS = (MODE==3)?768:192;
  if(MODE==0 || MODE==1){
    if(tid<128) rowmap[tid] = (MODE==0) ? wtok_to_prow(bm*128+tid) : wtok_to_row(bm*128+tid);
  }
  __syncthreads();
  f32x4 acc[4][4];
  #pragma unroll
  for(int i=0;i<4;i++)
    #pragma unroll
    for(int j=0;j<4;j++) acc[i][j] = (f32x4){0.f,0.f,0.f,0.f};

  constexpr int NCH = KTOT/64;
  auto STAGE = [&](int ch, int p){
    int k0 = ch*64;
    #pragma unroll
    for(int it=0; it<4; it++){
      int i = it*256 + wid*64 + l;
      int r = i>>3, sl = (i&7) ^ (r&7);
      size_t row = (size_t)((MODE==0||MODE==1) ? rowmap[r] : bm*128+r);
      gload16(A + row*RS + k0 + sl*8, &As[p][(size_t)(it*256+wid*64)*8]);
    }
    #pragma unroll
    for(int it=0; it<4; it++){
      int i = it*256 + wid*64 + l;
      int c = i>>3, sl = (i&7) ^ (c&7);
      gload16(Wb + (size_t)(bn*128+c)*KTOT + k0 + sl*8, &Bs[p][(size_t)(it*256+wid*64)*8]);
    }
  };
  STAGE(0,0);
  for(int ch=0; ch<NCH; ch++){
    if(ch+1<NCH){
      STAGE(ch+1,(ch+1)&1);
      asm volatile("s_waitcnt vmcnt(8)" ::: "memory");
    } else {
      asm volatile("s_waitcnt vmcnt(0)" ::: "memory");
    }
    __builtin_amdgcn_s_barrier();
    const short* as = As[ch&1];
    const short* bs = Bs[ch&1];
    #pragma unroll
    for(int ks=0; ks<2; ks++){
      short8 av[4], bv[4];
      #pragma unroll
      for(int i=0;i<4;i++){
        int r = wm*64 + i*16 + l15;
        av[i] = *(const short8*)&as[r*64 + (((ks*4+g) ^ (r&7))<<3)];
      }
      #pragma unroll
      for(int j=0;j<4;j++){
        int c = wn*64 + j*16 + l15;
        bv[j] = *(const short8*)&bs[c*64 + (((ks*4+g) ^ (c&7))<<3)];
      }
      #pragma unroll
      for(int i=0;i<4;i++)
        #pragma unroll
        for(int j=0;j<4;j++)
          acc[i][j] = __builtin_amdgcn_mfma_f32_16x16x32_bf16(av[i], bv[j], acc[i][j],0,0,0);
    }
    asm volatile("" ::: "memory");
    __builtin_amdgcn_s_barrier();
  }
  // ---- epilogue ----
  #pragma unroll
  for(int i=0;i<4;i++){
    int rloc0 = wm*64 + i*16 + g*4;
    #pragma unroll
    for(int j=0;j<4;j++){
      int o = bn*128 + wn*64 + j*16 + l15;
      if(MODE!=2 && o>=NOUT) continue;
      float bb = (o<NOUT) ? bias[o] : 0.f;
      #pragma unroll
      for(int reg=0; reg<4; reg++){
        int rl = rloc0 + reg;
        int trow = bm*128 + rl;
        float v = acc[i][j][reg] + bb;
        if(MODE==0){
          int which = o/180; int chn = o - which*180;
          int head = chn/30; int hd = chn - head*30;
          int win = trow>>9, n = trow&511;
          if(which==0){
            size_t sidx = ((size_t)(win*6+head)*512 + n)*32;
            ((short*)outv)[sidx + hd] = f2bf(v*SCALE_Q);
            if(hd==0) *(int*)&((short*)outv)[sidx + 30] = 0;
          } else if(which==1){
            size_t sidx = 6291456 + ((size_t)(win*6+head)*512 + n)*32;
            ((short*)outv)[sidx + hd] = f2bf(v);
            if(hd==0) *(int*)&((short*)outv)[sidx + 30] = 0;
          } else {
            ((short*)outv)[12582912 + ((size_t)(win*6+head)*32 + hd)*512 + n] = f2bf(v);
          }
        } else if(MODE==1){
          int grow = rowmap[rl];
          float conv = bf2f(((const short*)e1)[(size_t)grow*192 + o]);
          float am   = e2[(grow>>14)*180 + o];
          ((float*)outv)[(size_t)grow*180+o] = v + e0[(size_t)grow*180+o] + conv*am*0.01f;
        } else if(MODE==2){
          ((short*)outv)[(size_t)trow*768+o] = (o<720) ? f2bf(geluf(v)) : (short)0;
        } else {
          ((float*)outv)[(size_t)trow*180+o] = v + e0[(size_t)trow*180+o];
        }
      }
    }
  }
}

// ---------------- window attention: fixed-max softmax, bf16 MFMA ----------------
__global__ __launch_bounds__(256) void attn_mfma(const short* __restrict__ qkvb,
    const short* __restrict__ biasB, short* __restrict__ attnb){
  __shared__ short Ks[1024];
  __shared__ short Vt[1024];
  __shared__ short Ps[4096];
  int bid = blockIdx.x;
  int j0 = bid>>3;
  int grp = (bid&7)*48 + (j0>>2);
  int qt = j0&3;
  int win = grp/6, head = grp - (grp/6)*6;
  int tid = threadIdx.x, w = tid>>6, l = tid&63, l15 = l&15, g = l>>4;
  const short* qp = qkvb + (size_t)(win*6+head)*16384;
  const short* kp = qp + 6291456;
  const short* vp = qkvb + 12582912 + (size_t)(win*6+head)*16384;
  int qbase = qt*128 + w*32;
  short8 aq0 = *(const short8*)&qp[(size_t)(qbase + l15)*32 + g*8];
  short8 aq1 = *(const short8*)&qp[(size_t)(qbase + 16 + l15)*32 + g*8];
  const short* bB = biasB + ((size_t)head*512 + qbase)*512;
  f32x4 acc[2][2];
  float lsum[2][4];
  #pragma unroll
  for(int a=0;a<2;a++){
    #pragma unroll
    for(int r=0;r<4;r++) lsum[a][r]=0.f;
    #pragma unroll
    for(int b2=0;b2<2;b2++) acc[a][b2]=(f32x4){0.f,0.f,0.f,0.f};
  }
  int pbase = w*1024;
  int rrA = l15>>1, sA = ((l15&1)<<2)|g;
  int offT0 = rrA*64 + ((sA ^ (rrA&7))<<3);
  int rrB = 8+rrA;
  int offT1 = rrB*64 + ((sA ^ (rrB&7))<<3);
  int strr = (tid&127)>>3, sts = tid&7;
  int stoff = strr*64 + ((sts ^ (strr&7))<<3);
  int sttok = strr*2 + (sts>>2), sthd8 = (sts&3)*8;

  for(int kt=0; kt<16; kt++){
    if(tid<128){
      short8 v = *(const short8*)&kp[(size_t)(kt*32+sttok)*32 + sthd8];
      *(short8*)&Ks[stoff] = v;
    } else {
      short8 v = *(const short8*)&vp[(size_t)sttok*512 + kt*32 + sthd8];
      *(short8*)&Vt[stoff] = v;
    }
    unsigned ub[2][4];
    #pragma unroll
    for(int mf=0; mf<2; mf++)
      #pragma unroll
      for(int reg=0; reg<4; reg++)
        ub[mf][reg] = *(const unsigned*)&bB[(size_t)(mf*16+g*4+reg)*512 + kt*32 + 2*l15];
    __syncthreads();
    short8 bk0 = *(const short8*)&Ks[offT0];
    short8 bk1 = *(const short8*)&Ks[offT1];
    f32x4 z = (f32x4){0.f,0.f,0.f,0.f};
    f32x4 s00 = __builtin_amdgcn_mfma_f32_16x16x32_bf16(aq0, bk0, z,0,0,0);
    f32x4 s01 = __builtin_amdgcn_mfma_f32_16x16x32_bf16(aq0, bk1, z,0,0,0);
    f32x4 s10 = __builtin_amdgcn_mfma_f32_16x16x32_bf16(aq1, bk0, z,0,0,0);
    f32x4 s11 = __builtin_amdgcn_mfma_f32_16x16x32_bf16(aq1, bk1, z,0,0,0);
    #pragma unroll
    for(int mf=0; mf<2; mf++){
      #pragma unroll
      for(int reg=0; reg<4; reg++){
        float b0 = __uint_as_float(ub[mf][reg]<<16);
        float b1 = __uint_as_float(ub[mf][reg]&0xFFFF0000u);
        float sv0 = (mf==0)? s00[reg] : s10[reg];
        float sv1 = (mf==0)? s01[reg] : s11[reg];
        float p0 = __expf(fminf(sv0 + b0, 60.f));
        float p1 = __expf(fminf(sv1 + b1, 60.f));
        lsum[mf][reg] += p0 + p1;
        int q = mf*16 + g*4 + reg;
        int rr = q>>1;
        int s0 = ((q&1)<<2) | (l15>>3);
        int s1 = s0 + 2;
        Ps[pbase + rr*64 + ((s0 ^ (rr&7))<<3) + (l15&7)] = f2bf(p0);
        Ps[pbase + rr*64 + ((s1 ^ (rr&7))<<3) + (l15&7)] = f2bf(p1);
      }
    }
    short8 ap0 = *(const short8*)&Ps[pbase + offT0];
    short8 ap1 = *(const short8*)&Ps[pbase + offT1];
    short8 bv0 = *(const short8*)&Vt[offT0];
    short8 bv1 = *(const short8*)&Vt[offT1];
    acc[0][0] = __builtin_amdgcn_mfma_f32_16x16x32_bf16(ap0, bv0, acc[0][0],0,0,0);
    acc[0][1] = __builtin_amdgcn_mfma_f32_16x16x32_bf16(ap0, bv1, acc[0][1],0,0,0);
    acc[1][0] = __builtin_amdgcn_mfma_f32_16x16x32_bf16(ap1, bv0, acc[1][0],0,0,0);
    acc[1][1] = __builtin_amdgcn_mfma_f32_16x16x32_bf16(ap1, bv1, acc[1][1],0,0,0);
    __syncthreads();
  }
  int token = win*512 + qbase;
  #pragma unroll
  for(int mf=0; mf<2; mf++)
  #pragma unroll
  for(int reg=0; reg<4; reg++){
    float lv = lsum[mf][reg];
    lv += __shfl_xor(lv,1,64); lv += __shfl_xor(lv,2,64);
    lv += __shfl_xor(lv,4,64); lv += __shfl_xor(lv,8,64);
    float inv = 1.f/lv;
    int qg = token + mf*16 + g*4 + reg;
    short* orow = attnb + (size_t)qg*192 + head*30;
    if(l15<30) orow[l15] = f2bf(acc[mf][0][reg]*inv);
    if(l15<14) orow[16+l15] = f2bf(acc[mf][1][reg]*inv);
    if(head==5 && l15<12) attnb[(size_t)qg*192 + 180 + l15] = 0;
  }
}

// ---------------- launcher ----------------
extern "C" void kernel_launch(void* const* d_in, const int* in_sizes, int n_in,
                              void* d_out, int out_size, void* d_ws, size_t ws_size,
                              hipStream_t stream){
  const float* x      = (const float*)d_in[0];
  const int*   rpi    = (const int*)  d_in[4];
  const float* g1     = (const float*)d_in[7];
  const float* b1     = (const float*)d_in[8];
  const float* qkv_w  = (const float*)d_in[9];
  const float* qkv_b  = (const float*)d_in[10];
  const float* rpb    = (const float*)d_in[11];
  const float* proj_w = (const float*)d_in[12];
  const float* proj_b = (const float*)d_in[13];
  const float* cw1    = (const float*)d_in[14];
  const float* cb1    = (const float*)d_in[15];
  const float* cw2    = (const float*)d_in[16];
  const float* cb2    = (const float*)d_in[17];
  const float* caw1   = (const float*)d_in[18];
  const float* cab1   = (const float*)d_in[19];
  const float* caw2   = (const float*)d_in[20];
  const float* cab2   = (const float*)d_in[21];
  const float* g2     = (const float*)d_in[22];
  const float* b2     = (const float*)d_in[23];
  const float* fc1_w  = (const float*)d_in[24];
  const float* fc1_b  = (const float*)d_in[25];
  const float* fc2_w  = (const float*)d_in[26];
  const float* fc2_b  = (const float*)d_in[27];
  float* ws = (float*)d_ws;
  float* fout = (float*)d_out;
  short* attnb = (short*)(ws + OFF_ATTNB);
  short* xnp   = (short*)(ws + OFF_XNP);
  short* y1p   = (short*)(ws + OFF_Y1P);
  short* qkvb  = (short*)(ws + OFF_QKVB);
  short* hid   = (short*)(ws + OFF_HID);
  short* y2b   = (short*)(ws + OFF_Y2B);
  short* x2n   = (short*)(ws + OFF_X2N);
  short* biasB = (short*)(ws + OFF_BIASB);
  short* wq    = (short*)(ws + OFF_WQKV);
  short* wp    = (short*)(ws + OFF_WPROJ);
  short* w1    = (short*)(ws + OFF_WFC1);
  short* w2    = (short*)(ws + OFF_WFC2);
  short* wb1   = (short*)(ws + OFF_WB1);
  short* wb2   = (short*)(ws + OFF_WB2);

  hipMemsetAsync(xnp, 0, (size_t)7990272*2, stream);
  hipMemsetAsync(y1p, 0, (size_t)2663424*2, stream);
  prep_wb<<<2016,256,0,stream>>>(qkv_w, proj_w, fc1_w, fc2_w, wq, wp, w1, w2);
  prep_wbc<<<1296,256,0,stream>>>(cw1, cw2, wb1, wb2);
  bias_prep<<<1024,256,0,stream>>>(rpi, rpb, biasB);
  ln_bf16<1><<<8192,256,0,stream>>>(x, g1, b1, xnp);
  conv1_mfma<<<1024,256,0,stream>>>(xnp, wb1, cb1, y1p);
  conv2_mfma<<<1024,256,0,stream>>>(y1p, wb2, cb2, y2b);
  pool1_kernel<<<64,192,0,stream>>>(y2b, ws+OFF_PPART);
  pool2_kernel<<<2,256,0,stream>>>(ws+OFF_PPART, ws+OFF_POOL);
  chattn_kernel<<<1,64,0,stream>>>(ws+OFF_POOL, caw1, cab1, caw2, cab2, ws+OFF_AM);
  mgemm<0,540,192><<<dim3(256,5),256,0,stream>>>(
      xnp, wq, qkv_b, qkvb, nullptr, nullptr, nullptr);
  attn_mfma<<<1536,256,0,stream>>>(qkvb, biasB, attnb);
  mgemm<1,180,192><<<dim3(256,2),256,0,stream>>>(
      attnb, wp, proj_b, ws+OFF_X2, x, (const float*)y2b, ws+OFF_AM);
  ln_bf16<0><<<8192,256,0,stream>>>(ws+OFF_X2, g2, b2, x2n);
  mgemm<2,720,192><<<dim3(256,6),256,0,stream>>>(
      x2n, w1, fc1_b, hid, nullptr, nullptr, nullptr);
  mgemm<3,180,768><<<dim3(256,2),256,0,stream>>>(
      hid, w2, fc2_b, fout, ws+OFF_X2, nullptr, nullptr);
}

// Round 7
// 455.957 us; speedup vs baseline: 1.3997x; 1.3997x over previous
//
#include <hip/hip_runtime.h>
#include <math.h>

// ---------------- problem constants ----------------
static constexpr int CCH = 180;
static constexpr float SCALE_Q = 0.18257418583505536f; // 30^-0.5

typedef short short8 __attribute__((ext_vector_type(8)));
typedef float f32x4 __attribute__((ext_vector_type(4)));

// ---------------- ws layout (float offsets) ----------------
static constexpr size_t OFF_ATTNB = 0;         // bf16 32768x192
static constexpr size_t OFF_XNP   = 3145728;   // bf16 2x18x34x34x192 (3,995,136 f)
static constexpr size_t OFF_Y1P   = 7140864;   // bf16 2x18x34x34x64 (1,331,712 f)
static constexpr size_t OFF_QKVB  = 8472576;   // bf16 q,k:[384][512][32]x2, v:[384][32][512]
static constexpr size_t OFF_HID   = 0;         // bf16 32768x768 (12,582,912 f) aliases dead bufs
static constexpr size_t OFF_Y2B   = 17909760;  // bf16 32768x192
static constexpr size_t OFF_X2    = 21055488;  // f32 32768x180
static constexpr size_t OFF_X2N   = 26953728;  // bf16 32768x192
static constexpr size_t OFF_BIASB = 30099456;  // bf16 6x512x512
static constexpr size_t OFF_WQKV  = 30885888;  // bf16 640x192
static constexpr size_t OFF_WPROJ = 30947328;  // bf16 256x192
static constexpr size_t OFF_WFC1  = 30971904;  // bf16 768x192
static constexpr size_t OFF_WFC2  = 31045632;  // bf16 256x768
static constexpr size_t OFF_WB1   = 31143936;  // bf16 27x64x192
static constexpr size_t OFF_WB2   = 31309824;  // bf16 27x192x64
static constexpr size_t OFF_PPART = 31475712;  // f32 64x180
static constexpr size_t OFF_POOL  = 31487232;  // 360
static constexpr size_t OFF_AM    = 31487592;  // 360 -> end ~126 MiB

__device__ __forceinline__ float geluf(float v){
  return 0.5f*v*(1.0f + erff(v*0.70710678118654752440f));
}
__device__ __forceinline__ short f2bf(float f){
  unsigned u = __float_as_uint(f);
  unsigned r = (u + 0x7FFFu + ((u>>16)&1u)) >> 16;
  return (short)r;
}
__device__ __forceinline__ float bf2f(short s){
  return __uint_as_float(((unsigned)(unsigned short)s)<<16);
}
__device__ __forceinline__ void gload16(const void* g, void* l){
  __builtin_amdgcn_global_load_lds(
    (const __attribute__((address_space(1))) unsigned int*)g,
    (__attribute__((address_space(3))) unsigned int*)l, 16, 0, 0);
}

// ---------------- gemm weights -> padded bf16 ----------------
__global__ void prep_wb(const float* __restrict__ qkv_w, const float* __restrict__ proj_w,
                        const float* __restrict__ fc1_w, const float* __restrict__ fc2_w,
                        short* __restrict__ wq, short* __restrict__ wp,
                        short* __restrict__ w1, short* __restrict__ w2){
  int i = blockIdx.x*256 + threadIdx.x;
  if(i < 122880){
    int o = i/192, k = i - o*192;
    wq[i] = (o<540 && k<180) ? f2bf(qkv_w[o*180+k]) : (short)0;
  } else if(i < 172032){
    int j = i-122880; int o = j/192, k = j - o*192;
    wp[j] = (o<180 && k<180) ? f2bf(proj_w[o*180+k]) : (short)0;
  } else if(i < 319488){
    int j = i-172032; int o = j/192, k = j - o*192;
    w1[j] = (o<720 && k<180) ? f2bf(fc1_w[o*180+k]) : (short)0;
  } else if(i < 516096){
    int j = i-319488; int o = j/768, k = j - o*768;
    w2[j] = (o<180 && k<720) ? f2bf(fc2_w[o*720+k]) : (short)0;
  }
}

// ---------------- conv weights -> bf16 [tap][co][ci] padded ----------------
__global__ void prep_wbc(const float* __restrict__ cw1, const float* __restrict__ cw2,
                         short* __restrict__ wb1, short* __restrict__ wb2){
  int i = blockIdx.x*256 + threadIdx.x;
  if(i < 27*64*192){
    int t = i/(64*192); int rem = i - t*64*192;
    int co = rem/192, ci = rem - co*192;
    wb1[i] = (co<60 && ci<180) ? f2bf(cw1[(co*180+ci)*27 + t]) : (short)0;
    int co2 = rem/64, ci2 = rem - co2*64;
    wb2[i] = (co2<180 && ci2<60) ? f2bf(cw2[(co2*60+ci2)*27 + t]) : (short)0;
  }
}

// ---------------- bias table -> packed bf16 pairs ----------------
__global__ __launch_bounds__(256) void bias_prep(const int* __restrict__ rpi,
    const float* __restrict__ rpb, short* __restrict__ biasB){
  int i = blockIdx.x*256 + threadIdx.x;   // q*512+k
  int q = i>>9, k = i&511;
  int kt = k>>5, kin = k&31;
  int j = kt*32 + ((kin<16) ? 2*kin : 2*(kin-16)+1);
  int idx = rpi[i];
  #pragma unroll
  for(int h=0;h<6;h++)
    biasB[((size_t)h*512 + q)*512 + j] = f2bf(rpb[idx*6+h]);
}

// ---------------- layernorm -> bf16 (padded xnp or compact 192) ----------------
template<int PADDED>
__global__ __launch_bounds__(256) void ln_bf16(const float* __restrict__ x,
    const float* __restrict__ g, const float* __restrict__ b, short* __restrict__ outb){
  int token = blockIdx.x*4 + (threadIdx.x>>6);
  int lane  = threadIdx.x & 63;
  const float* row = x + (size_t)token*CCH;
  float v0 = row[lane], v1 = row[lane+64];
  float v2 = (lane<52) ? row[lane+128] : 0.f;
  float s = v0+v1+v2;
  #pragma unroll
  for(int m=1;m<64;m<<=1) s += __shfl_xor(s, m, 64);
  float mean = s*(1.f/180.f);
  float d0=v0-mean, d1=v1-mean, d2=(lane<52)?(v2-mean):0.f;
  float sq = d0*d0+d1*d1+d2*d2;
  #pragma unroll
  for(int m=1;m<64;m<<=1) sq += __shfl_xor(sq, m, 64);
  float rstd = rsqrtf(sq*(1.f/180.f)+1e-5f);
  size_t orow;
  if(PADDED){
    int bb=token>>14, d=(token>>10)&15, h=(token>>5)&31, w=token&31;
    orow = ((size_t)((bb*18+d+1)*34 + h+1)*34 + w+1)*192;
  } else {
    orow = (size_t)token*192;
  }
  short* o = outb + orow;
  o[lane]    = f2bf(d0*rstd*g[lane]    + b[lane]);
  o[lane+64] = f2bf(d1*rstd*g[lane+64] + b[lane+64]);
  o[lane+128]= (lane<52) ? f2bf(d2*rstd*g[lane+128] + b[lane+128]) : (short)0;
}

// ---------------- conv1: 192->64, M=64 tile, co-split waves ----------------
// block = (b,d,h0..h0+1): 64 tokens. wave w owns co w*16..w*16+15.
// 648 MFMA / 162 weight-loads per wave (ratio 4).
__global__ __launch_bounds__(256) void conv1_mfma(const short* __restrict__ in,
    const short* __restrict__ wb, const float* __restrict__ cbias, short* __restrict__ y1p){
  __shared__ short lds[26112];   // 4 h-rows x 34 w x 192 ci, XOR-swizzled
  int bid = blockIdx.x;
  int xcd = bid&7, idx = bid>>3;
  int b = idx>>5, dd=(idx>>4)&1, hg=idx&15;
  int d = xcd*2+dd;
  int h0 = hg*2;
  int tid=threadIdx.x, l=tid&63, l15=l&15, g=l>>4, wid=tid>>6;
  int soff[13];
  #pragma unroll
  for(int it=0; it<13; it++){
    int t = it*256 + tid;
    int rr = t/24, s = t - rr*24;
    soff[it] = rr*192 + (((s&~7)|((s&7)^(rr&7)))<<3);
  }
  f32x4 acc[4];
  #pragma unroll
  for(int mi=0;mi<4;mi++) acc[mi]=(f32x4){0.f,0.f,0.f,0.f};
  for(int kd=0;kd<3;kd++){
    {  // stage 4 contiguous padded h-rows (h0-1..h0+2 -> padded h0..h0+3)
      const short* S = in + (((size_t)(b*18+d+kd)*34 + h0)*34)*192;
      #pragma unroll
      for(int it=0; it<13; it++){
        if(it<12 || tid<192)
          gload16(S + soff[it], &lds[(it*256 + wid*64)*8]);
      }
    }
    __syncthreads();
    #pragma unroll
    for(int kh=0;kh<3;kh++)
    #pragma unroll
    for(int kw=0;kw<3;kw++){
      const short* wt = wb + (size_t)((kd*3+kh)*3+kw)*12288 + (wid*16+l15)*192;
      #pragma unroll
      for(int ks=0;ks<6;ks++){
        int s = ks*4+g;
        short8 bv = *(const short8*)&wt[ks*32 + g*8];
        #pragma unroll
        for(int mi=0;mi<4;mi++){
          int R = ((mi>>1)+kh)*34 + (mi&1)*16 + l15 + kw;
          short8 av = *(const short8*)&lds[R*192 + (((s&~7)|((s&7)^(R&7)))<<3)];
          acc[mi] = __builtin_amdgcn_mfma_f32_16x16x32_bf16(av, bv, acc[mi],0,0,0);
        }
      }
    }
    __syncthreads();
  }
  int co = wid*16+l15;
  float bb = (co<60)? cbias[co] : 0.f;
  #pragma unroll
  for(int mi=0;mi<4;mi++){
    int hr = mi>>1;
    #pragma unroll
    for(int reg=0;reg<4;reg++){
      int r = mi*16 + g*4 + reg;
      int w = r&31;
      y1p[(((size_t)(b*18+d+1)*34 + h0+hr+1)*34 + w+1)*64 + co] = f2bf(geluf(acc[mi][reg] + bb));
    }
  }
}

// ---------------- conv2: 64->192, M=64 tile, co-split waves ----------------
__global__ __launch_bounds__(256) void conv2_mfma(const short* __restrict__ in,
    const short* __restrict__ wb, const float* __restrict__ cbias, short* __restrict__ y2b){
  __shared__ short lds[8704];   // 4 h-rows x 34 w x 64 ci
  int bid = blockIdx.x;
  int xcd = bid&7, idx = bid>>3;
  int b = idx>>5, dd=(idx>>4)&1, hg=idx&15;
  int d = xcd*2+dd;
  int h0 = hg*2;
  int tid=threadIdx.x, l=tid&63, l15=l&15, g=l>>4, wid=tid>>6;
  int soff[5];
  #pragma unroll
  for(int it=0; it<5; it++){
    int t = it*256 + tid;
    int rr = t>>3, s = t&7;
    soff[it] = rr*64 + ((s^(rr&7))<<3);
  }
  f32x4 acc[4][3];
  #pragma unroll
  for(int mi=0;mi<4;mi++)
    #pragma unroll
    for(int nj=0;nj<3;nj++) acc[mi][nj]=(f32x4){0.f,0.f,0.f,0.f};
  for(int kd=0;kd<3;kd++){
    {
      const short* S = in + (((size_t)(b*18+d+kd)*34 + h0)*34)*64;
      #pragma unroll
      for(int it=0; it<5; it++){
        if(it<4 || tid<64)
          gload16(S + soff[it], &lds[(it*256 + wid*64)*8]);
      }
    }
    __syncthreads();
    #pragma unroll
    for(int kh=0;kh<3;kh++)
    #pragma unroll
    for(int kw=0;kw<3;kw++){
      const short* wt = wb + (size_t)((kd*3+kh)*3+kw)*12288;
      #pragma unroll
      for(int ks=0;ks<2;ks++){
        int s = ks*4+g;
        short8 bv[3];
        #pragma unroll
        for(int nj=0;nj<3;nj++)
          bv[nj] = *(const short8*)&wt[(size_t)(wid*48+nj*16+l15)*64 + ks*32 + g*8];
        #pragma unroll
        for(int mi=0;mi<4;mi++){
          int R = ((mi>>1)+kh)*34 + (mi&1)*16 + l15 + kw;
          short8 av = *(const short8*)&lds[R*64 + ((s^(R&7))<<3)];
          #pragma unroll
          for(int nj=0;nj<3;nj++)
            acc[mi][nj] = __builtin_amdgcn_mfma_f32_16x16x32_bf16(av, bv[nj], acc[mi][nj],0,0,0);
        }
      }
    }
    __syncthreads();
  }
  #pragma unroll
  for(int nj=0;nj<3;nj++){
    int co = wid*48 + nj*16 + l15;
    if(co<180){
      float bb = cbias[co];
      #pragma unroll
      for(int mi=0;mi<4;mi++){
        int hr = mi>>1;
        #pragma unroll
        for(int reg=0;reg<4;reg++){
          int r = mi*16 + g*4 + reg;
          int w = r&31;
          size_t token = ((size_t)(b*16+d)*32 + h0+hr)*32 + w;
          y2b[token*192 + co] = f2bf(acc[mi][nj][reg] + bb);
        }
      }
    }
  }
}

// ---------------- pool (2-stage) ----------------
__global__ __launch_bounds__(192) void pool1_kernel(const short* __restrict__ y2b,
                                                    float* __restrict__ part){
  int b = blockIdx.x>>5, chunk = blockIdx.x&31;
  int c = threadIdx.x;
  if(c<180){
    float s = 0.f;
    const short* base = y2b + ((size_t)b*16384 + chunk*512)*192 + c;
    for(int it=0;it<512;it++) s += bf2f(base[(size_t)it*192]);
    part[blockIdx.x*180 + c] = s;
  }
}
__global__ void pool2_kernel(const float* __restrict__ part, float* __restrict__ pooled){
  int i = blockIdx.x*256 + threadIdx.x;
  if(i<360){
    int b = i/180, c = i - b*180;
    float s = 0.f;
    for(int ch=0;ch<32;ch++) s += part[(b*32+ch)*180 + c];
    pooled[i] = s*(1.f/16384.f);
  }
}

// ---------------- channel attention (tiny) ----------------
__global__ void chattn_kernel(const float* __restrict__ pooled,
    const float* __restrict__ caw1, const float* __restrict__ cab1,
    const float* __restrict__ caw2, const float* __restrict__ cab2,
    float* __restrict__ amask){
  __shared__ float hid[2][6];
  int t = threadIdx.x;
  if(t<12){
    int b = t/6, qh = t - b*6;
    float s = cab1[qh];
    for(int c=0;c<180;c++) s += pooled[b*180+c]*caw1[qh*180+c];
    hid[b][qh] = fmaxf(s, 0.f);
  }
  __syncthreads();
  for(int i=t;i<360;i+=64){
    int b = i/180, c = i - b*180;
    float s = cab2[c];
    #pragma unroll
    for(int qh=0;qh<6;qh++) s += hid[b][qh]*caw2[c*6+qh];
    amask[i] = 1.f/(1.f+__expf(-s));
  }
}

// ---------------- window-token <-> row mappings ----------------
__device__ __forceinline__ void wtok_decomp(int t, int& b, int& dd, int& hh, int& ww){
  int win = t >> 9, n = t & 511;
  int sb = win >> 2, wi = win & 3;
  int wh = wi >> 1, wwi = wi & 1;
  b = sb >> 3; int r = sb & 7;
  int id = r >> 2, ih = (r>>1)&1, iw = r&1;
  int td = n >> 6, th = (n>>3)&7, tw = n & 7;
  dd = td*2 + id;
  hh = (wh*8+th)*2 + ih;
  ww = (wwi*8+tw)*2 + iw;
}
__device__ __forceinline__ int wtok_to_row(int t){
  int b,dd,hh,ww; wtok_decomp(t,b,dd,hh,ww);
  return b*16384 + (dd*32+hh)*32 + ww;
}
__device__ __forceinline__ int wtok_to_prow(int t){
  int b,dd,hh,ww; wtok_decomp(t,b,dd,hh,ww);
  return ((b*18+dd+1)*34 + hh+1)*34 + ww + 1;
}

// ---------------- bf16 MFMA GEMM 128x128, gload_lds dbuf pipeline ----------------
template<int MODE, int NOUT, int KTOT>
__global__ __launch_bounds__(256) void mgemm(const short* __restrict__ A,
    const short* __restrict__ Wb, const float* __restrict__ bias, void* __restrict__ outv,
    const float* __restrict__ e0, const float* __restrict__ e1,
    const float* __restrict__ e2){
  __shared__ short As[2][8192];
  __shared__ short Bs[2][8192];
  __shared__ int rowmap[128];
  int lin = blockIdx.y*gridDim.x + blockIdx.x;
  int xcd = lin&7, k = lin>>3;
  int bm = xcd*32 + (k & 31);
  int bn = k >> 5;
  int tid = threadIdx.x;
  int l = tid&63, l15=l&15, g=l>>4, wid=tid>>6;
  int wm = wid>>1, wn = wid&1;
  constexpr int RS = (MODE==3)?768:192;
  if(MODE==0 || MODE==1){
    if(tid<128) rowmap[tid] = (MODE==0) ? wtok_to_prow(bm*128+tid) : wtok_to_row(bm*128+tid);
  }
  __syncthreads();
  f32x4 acc[4][4];
  #pragma unroll
  for(int i=0;i<4;i++)
    #pragma unroll
    for(int j=0;j<4;j++) acc[i][j] = (f32x4){0.f,0.f,0.f,0.f};

  constexpr int NCH = KTOT/64;
  auto STAGE = [&](int ch, int p){
    int k0 = ch*64;
    #pragma unroll
    for(int it=0; it<4; it++){
      int i = it*256 + wid*64 + l;
      int r = i>>3, sl = (i&7) ^ (r&7);
      size_t row = (size_t)((MODE==0||MODE==1) ? rowmap[r] : bm*128+r);
      gload16(A + row*RS + k0 + sl*8, &As[p][(size_t)(it*256+wid*64)*8]);
    }
    #pragma unroll
    for(int it=0; it<4; it++){
      int i = it*256 + wid*64 + l;
      int c = i>>3, sl = (i&7) ^ (c&7);
      gload16(Wb + (size_t)(bn*128+c)*KTOT + k0 + sl*8, &Bs[p][(size_t)(it*256+wid*64)*8]);
    }
  };
  STAGE(0,0);
  for(int ch=0; ch<NCH; ch++){
    if(ch+1<NCH){
      STAGE(ch+1,(ch+1)&1);
      asm volatile("s_waitcnt vmcnt(8)" ::: "memory");
    } else {
      asm volatile("s_waitcnt vmcnt(0)" ::: "memory");
    }
    __builtin_amdgcn_s_barrier();
    const short* as = As[ch&1];
    const short* bs = Bs[ch&1];
    #pragma unroll
    for(int ks=0; ks<2; ks++){
      short8 av[4], bv[4];
      #pragma unroll
      for(int i=0;i<4;i++){
        int r = wm*64 + i*16 + l15;
        av[i] = *(const short8*)&as[r*64 + (((ks*4+g) ^ (r&7))<<3)];
      }
      #pragma unroll
      for(int j=0;j<4;j++){
        int c = wn*64 + j*16 + l15;
        bv[j] = *(const short8*)&bs[c*64 + (((ks*4+g) ^ (c&7))<<3)];
      }
      #pragma unroll
      for(int i=0;i<4;i++)
        #pragma unroll
        for(int j=0;j<4;j++)
          acc[i][j] = __builtin_amdgcn_mfma_f32_16x16x32_bf16(av[i], bv[j], acc[i][j],0,0,0);
    }
    asm volatile("" ::: "memory");
    __builtin_amdgcn_s_barrier();
  }
  // ---- epilogue ----
  #pragma unroll
  for(int i=0;i<4;i++){
    int rloc0 = wm*64 + i*16 + g*4;
    #pragma unroll
    for(int j=0;j<4;j++){
      int o = bn*128 + wn*64 + j*16 + l15;
      if(MODE!=2 && o>=NOUT) continue;
      float bb = (o<NOUT) ? bias[o] : 0.f;
      #pragma unroll
      for(int reg=0; reg<4; reg++){
        int rl = rloc0 + reg;
        int trow = bm*128 + rl;
        float v = acc[i][j][reg] + bb;
        if(MODE==0){
          int which = o/180; int chn = o - which*180;
          int head = chn/30; int hd = chn - head*30;
          int win = trow>>9, n = trow&511;
          if(which==0){
            size_t sidx = ((size_t)(win*6+head)*512 + n)*32;
            ((short*)outv)[sidx + hd] = f2bf(v*SCALE_Q);
            if(hd==0) *(int*)&((short*)outv)[sidx + 30] = 0;
          } else if(which==1){
            size_t sidx = 6291456 + ((size_t)(win*6+head)*512 + n)*32;
            ((short*)outv)[sidx + hd] = f2bf(v);
            if(hd==0) *(int*)&((short*)outv)[sidx + 30] = 0;
          } else {
            ((short*)outv)[12582912 + ((size_t)(win*6+head)*32 + hd)*512 + n] = f2bf(v);
          }
        } else if(MODE==1){
          int grow = rowmap[rl];
          float conv = bf2f(((const short*)e1)[(size_t)grow*192 + o]);
          float am   = e2[(grow>>14)*180 + o];
          ((float*)outv)[(size_t)grow*180+o] = v + e0[(size_t)grow*180+o] + conv*am*0.01f;
        } else if(MODE==2){
          ((short*)outv)[(size_t)trow*768+o] = (o<720) ? f2bf(geluf(v)) : (short)0;
        } else {
          ((float*)outv)[(size_t)trow*180+o] = v + e0[(size_t)trow*180+o];
        }
      }
    }
  }
}

// ---------------- window attention: fixed-max softmax, bf16 MFMA ----------------
__global__ __launch_bounds__(256) void attn_mfma(const short* __restrict__ qkvb,
    const short* __restrict__ biasB, short* __restrict__ attnb){
  __shared__ short Ks[1024];
  __shared__ short Vt[1024];
  __shared__ short Ps[4096];
  int bid = blockIdx.x;
  int j0 = bid>>3;
  int grp = (bid&7)*48 + (j0>>2);
  int qt = j0&3;
  int win = grp/6, head = grp - (grp/6)*6;
  int tid = threadIdx.x, w = tid>>6, l = tid&63, l15 = l&15, g = l>>4;
  const short* qp = qkvb + (size_t)(win*6+head)*16384;
  const short* kp = qp + 6291456;
  const short* vp = qkvb + 12582912 + (size_t)(win*6+head)*16384;
  int qbase = qt*128 + w*32;
  short8 aq0 = *(const short8*)&qp[(size_t)(qbase + l15)*32 + g*8];
  short8 aq1 = *(const short8*)&qp[(size_t)(qbase + 16 + l15)*32 + g*8];
  const short* bB = biasB + ((size_t)head*512 + qbase)*512;
  f32x4 acc[2][2];
  float lsum[2][4];
  #pragma unroll
  for(int a=0;a<2;a++){
    #pragma unroll
    for(int r=0;r<4;r++) lsum[a][r]=0.f;
    #pragma unroll
    for(int b2=0;b2<2;b2++) acc[a][b2]=(f32x4){0.f,0.f,0.f,0.f};
  }
  int pbase = w*1024;
  int rrA = l15>>1, sA = ((l15&1)<<2)|g;
  int offT0 = rrA*64 + ((sA ^ (rrA&7))<<3);
  int rrB = 8+rrA;
  int offT1 = rrB*64 + ((sA ^ (rrB&7))<<3);
  int strr = (tid&127)>>3, sts = tid&7;
  int stoff = strr*64 + ((sts ^ (strr&7))<<3);
  int sttok = strr*2 + (sts>>2), sthd8 = (sts&3)*8;

  for(int kt=0; kt<16; kt++){
    if(tid<128){
      short8 v = *(const short8*)&kp[(size_t)(kt*32+sttok)*32 + sthd8];
      *(short8*)&Ks[stoff] = v;
    } else {
      short8 v = *(const short8*)&vp[(size_t)sttok*512 + kt*32 + sthd8];
      *(short8*)&Vt[stoff] = v;
    }
    unsigned ub[2][4];
    #pragma unroll
    for(int mf=0; mf<2; mf++)
      #pragma unroll
      for(int reg=0; reg<4; reg++)
        ub[mf][reg] = *(const unsigned*)&bB[(size_t)(mf*16+g*4+reg)*512 + kt*32 + 2*l15];
    __syncthreads();
    short8 bk0 = *(const short8*)&Ks[offT0];
    short8 bk1 = *(const short8*)&Ks[offT1];
    f32x4 z = (f32x4){0.f,0.f,0.f,0.f};
    f32x4 s00 = __builtin_amdgcn_mfma_f32_16x16x32_bf16(aq0, bk0, z,0,0,0);
    f32x4 s01 = __builtin_amdgcn_mfma_f32_16x16x32_bf16(aq0, bk1, z,0,0,0);
    f32x4 s10 = __builtin_amdgcn_mfma_f32_16x16x32_bf16(aq1, bk0, z,0,0,0);
    f32x4 s11 = __builtin_amdgcn_mfma_f32_16x16x32_bf16(aq1, bk1, z,0,0,0);
    #pragma unroll
    for(int mf=0; mf<2; mf++){
      #pragma unroll
      for(int reg=0; reg<4; reg++){
        float b0 = __uint_as_float(ub[mf][reg]<<16);
        float b1 = __uint_as_float(ub[mf][reg]&0xFFFF0000u);
        float sv0 = (mf==0)? s00[reg] : s10[reg];
        float sv1 = (mf==0)? s01[reg] : s11[reg];
        float p0 = __expf(fminf(sv0 + b0, 60.f));
        float p1 = __expf(fminf(sv1 + b1, 60.f));
        lsum[mf][reg] += p0 + p1;
        int q = mf*16 + g*4 + reg;
        int rr = q>>1;
        int s0 = ((q&1)<<2) | (l15>>3);
        int s1 = s0 + 2;
        Ps[pbase + rr*64 + ((s0 ^ (rr&7))<<3) + (l15&7)] = f2bf(p0);
        Ps[pbase + rr*64 + ((s1 ^ (rr&7))<<3) + (l15&7)] = f2bf(p1);
      }
    }
    short8 ap0 = *(const short8*)&Ps[pbase + offT0];
    short8 ap1 = *(const short8*)&Ps[pbase + offT1];
    short8 bv0 = *(const short8*)&Vt[offT0];
    short8 bv1 = *(const short8*)&Vt[offT1];
    acc[0][0] = __builtin_amdgcn_mfma_f32_16x16x32_bf16(ap0, bv0, acc[0][0],0,0,0);
    acc[0][1] = __builtin_amdgcn_mfma_f32_16x16x32_bf16(ap0, bv1, acc[0][1],0,0,0);
    acc[1][0] = __builtin_amdgcn_mfma_f32_16x16x32_bf16(ap1, bv0, acc[1][0],0,0,0);
    acc[1][1] = __builtin_amdgcn_mfma_f32_16x16x32_bf16(ap1, bv1, acc[1][1],0,0,0);
    __syncthreads();
  }
  int token = win*512 + qbase;
  #pragma unroll
  for(int mf=0; mf<2; mf++)
  #pragma unroll
  for(int reg=0; reg<4; reg++){
    float lv = lsum[mf][reg];
    lv += __shfl_xor(lv,1,64); lv += __shfl_xor(lv,2,64);
    lv += __shfl_xor(lv,4,64); lv += __shfl_xor(lv,8,64);
    float inv = 1.f/lv;
    int qg = token + mf*16 + g*4 + reg;
    short* orow = attnb + (size_t)qg*192 + head*30;
    if(l15<30) orow[l15] = f2bf(acc[mf][0][reg]*inv);
    if(l15<14) orow[16+l15] = f2bf(acc[mf][1][reg]*inv);
    if(head==5 && l15<12) attnb[(size_t)qg*192 + 180 + l15] = 0;
  }
}

// ---------------- launcher ----------------
extern "C" void kernel_launch(void* const* d_in, const int* in_sizes, int n_in,
                              void* d_out, int out_size, void* d_ws, size_t ws_size,
                              hipStream_t stream){
  const float* x      = (const float*)d_in[0];
  const int*   rpi    = (const int*)  d_in[4];
  const float* g1     = (const float*)d_in[7];
  const float* b1     = (const float*)d_in[8];
  const float* qkv_w  = (const float*)d_in[9];
  const float* qkv_b  = (const float*)d_in[10];
  const float* rpb    = (const float*)d_in[11];
  const float* proj_w = (const float*)d_in[12];
  const float* proj_b = (const float*)d_in[13];
  const float* cw1    = (const float*)d_in[14];
  const float* cb1    = (const float*)d_in[15];
  const float* cw2    = (const float*)d_in[16];
  const float* cb2    = (const float*)d_in[17];
  const float* caw1   = (const float*)d_in[18];
  const float* cab1   = (const float*)d_in[19];
  const float* caw2   = (const float*)d_in[20];
  const float* cab2   = (const float*)d_in[21];
  const float* g2     = (const float*)d_in[22];
  const float* b2     = (const float*)d_in[23];
  const float* fc1_w  = (const float*)d_in[24];
  const float* fc1_b  = (const float*)d_in[25];
  const float* fc2_w  = (const float*)d_in[26];
  const float* fc2_b  = (const float*)d_in[27];
  float* ws = (float*)d_ws;
  float* fout = (float*)d_out;
  short* attnb = (short*)(ws + OFF_ATTNB);
  short* xnp   = (short*)(ws + OFF_XNP);
  short* y1p   = (short*)(ws + OFF_Y1P);
  short* qkvb  = (short*)(ws + OFF_QKVB);
  short* hid   = (short*)(ws + OFF_HID);
  short* y2b   = (short*)(ws + OFF_Y2B);
  short* x2n   = (short*)(ws + OFF_X2N);
  short* biasB = (short*)(ws + OFF_BIASB);
  short* wq    = (short*)(ws + OFF_WQKV);
  short* wp    = (short*)(ws + OFF_WPROJ);
  short* w1    = (short*)(ws + OFF_WFC1);
  short* w2    = (short*)(ws + OFF_WFC2);
  short* wb1   = (short*)(ws + OFF_WB1);
  short* wb2   = (short*)(ws + OFF_WB2);

  hipMemsetAsync(xnp, 0, (size_t)7990272*2, stream);
  hipMemsetAsync(y1p, 0, (size_t)2663424*2, stream);
  prep_wb<<<2016,256,0,stream>>>(qkv_w, proj_w, fc1_w, fc2_w, wq, wp, w1, w2);
  prep_wbc<<<1296,256,0,stream>>>(cw1, cw2, wb1, wb2);
  bias_prep<<<1024,256,0,stream>>>(rpi, rpb, biasB);
  ln_bf16<1><<<8192,256,0,stream>>>(x, g1, b1, xnp);
  conv1_mfma<<<512,256,0,stream>>>(xnp, wb1, cb1, y1p);
  conv2_mfma<<<512,256,0,stream>>>(y1p, wb2, cb2, y2b);
  pool1_kernel<<<64,192,0,stream>>>(y2b, ws+OFF_PPART);
  pool2_kernel<<<2,256,0,stream>>>(ws+OFF_PPART, ws+OFF_POOL);
  chattn_kernel<<<1,64,0,stream>>>(ws+OFF_POOL, caw1, cab1, caw2, cab2, ws+OFF_AM);
  mgemm<0,540,192><<<dim3(256,5),256,0,stream>>>(
      xnp, wq, qkv_b, qkvb, nullptr, nullptr, nullptr);
  attn_mfma<<<1536,256,0,stream>>>(qkvb, biasB, attnb);
  mgemm<1,180,192><<<dim3(256,2),256,0,stream>>>(
      attnb, wp, proj_b, ws+OFF_X2, x, (const float*)y2b, ws+OFF_AM);
  ln_bf16<0><<<8192,256,0,stream>>>(ws+OFF_X2, g2, b2, x2n);
  mgemm<2,720,192><<<dim3(256,6),256,0,stream>>>(
      x2n, w1, fc1_b, hid, nullptr, nullptr, nullptr);
  mgemm<3,180,768><<<dim3(256,2),256,0,stream>>>(
      hid, w2, fc2_b, fout, ws+OFF_X2, nullptr, nullptr);
}

// Round 10
// 448.547 us; speedup vs baseline: 1.4228x; 1.0165x over previous
//
#include <hip/hip_runtime.h>
#include <math.h>

// ---------------- problem constants ----------------
static constexpr int CCH = 180;
static constexpr float SCALE_Q = 0.18257418583505536f; // 30^-0.5

typedef short short8 __attribute__((ext_vector_type(8)));
typedef float f32x4 __attribute__((ext_vector_type(4)));

// ---------------- ws layout (float offsets) ----------------
static constexpr size_t OFF_ATTNB = 0;         // bf16 32768x192
static constexpr size_t OFF_XNP   = 3145728;   // bf16 2x18x34x34x192
static constexpr size_t OFF_Y1P   = 7140864;   // bf16 2x18x34x34x64
static constexpr size_t OFF_QKVB  = 8472576;   // bf16 q,k:[384][512][32]x2, v:[384][32][512]
static constexpr size_t OFF_HID   = 0;         // bf16 32768x768 (aliases dead bufs)
static constexpr size_t OFF_Y2B   = 17909760;  // bf16 32768x192
static constexpr size_t OFF_X2    = 21055488;  // f32 32768x180
static constexpr size_t OFF_X2N   = 26953728;  // bf16 32768x192
static constexpr size_t OFF_BIASB = 30099456;  // bf16 6x512x512
static constexpr size_t OFF_WQKV  = 30885888;  // bf16 640x192
static constexpr size_t OFF_WPROJ = 30947328;  // bf16 256x192
static constexpr size_t OFF_WFC1  = 30971904;  // bf16 768x192
static constexpr size_t OFF_WFC2  = 31045632;  // bf16 256x768
static constexpr size_t OFF_WB1   = 31143936;  // bf16 27x64x192
static constexpr size_t OFF_WB2   = 31309824;  // bf16 27x192x64
static constexpr size_t OFF_POOL  = 31475712;  // f32 360
static constexpr size_t OFF_AM    = 31476072;  // f32 360

__device__ __forceinline__ float geluf(float v){
  return 0.5f*v*(1.0f + erff(v*0.70710678118654752440f));
}
__device__ __forceinline__ short f2bf(float f){
  unsigned u = __float_as_uint(f);
  unsigned r = (u + 0x7FFFu + ((u>>16)&1u)) >> 16;
  return (short)r;
}
__device__ __forceinline__ float bf2f(short s){
  return __uint_as_float(((unsigned)(unsigned short)s)<<16);
}
__device__ __forceinline__ void gload16(const void* g, void* l){
  __builtin_amdgcn_global_load_lds(
    (const __attribute__((address_space(1))) unsigned int*)g,
    (__attribute__((address_space(3))) unsigned int*)l, 16, 0, 0);
}

// ---------------- gemm weights -> padded bf16 ----------------
__global__ void prep_wb(const float* __restrict__ qkv_w, const float* __restrict__ proj_w,
                        const float* __restrict__ fc1_w, const float* __restrict__ fc2_w,
                        short* __restrict__ wq, short* __restrict__ wp,
                        short* __restrict__ w1, short* __restrict__ w2){
  int i = blockIdx.x*256 + threadIdx.x;
  if(i < 122880){
    int o = i/192, k = i - o*192;
    wq[i] = (o<540 && k<180) ? f2bf(qkv_w[o*180+k]) : (short)0;
  } else if(i < 172032){
    int j = i-122880; int o = j/192, k = j - o*192;
    wp[j] = (o<180 && k<180) ? f2bf(proj_w[o*180+k]) : (short)0;
  } else if(i < 319488){
    int j = i-172032; int o = j/192, k = j - o*192;
    w1[j] = (o<720 && k<180) ? f2bf(fc1_w[o*180+k]) : (short)0;
  } else if(i < 516096){
    int j = i-319488; int o = j/768, k = j - o*768;
    w2[j] = (o<180 && k<720) ? f2bf(fc2_w[o*720+k]) : (short)0;
  }
}

// ---------------- conv weights -> bf16 [tap][co][ci] padded ----------------
__global__ void prep_wbc(const float* __restrict__ cw1, const float* __restrict__ cw2,
                         short* __restrict__ wb1, short* __restrict__ wb2){
  int i = blockIdx.x*256 + threadIdx.x;
  if(i < 27*64*192){
    int t = i/(64*192); int rem = i - t*64*192;
    int co = rem/192, ci = rem - co*192;
    wb1[i] = (co<60 && ci<180) ? f2bf(cw1[(co*180+ci)*27 + t]) : (short)0;
    int co2 = rem/64, ci2 = rem - co2*64;
    wb2[i] = (co2<180 && ci2<60) ? f2bf(cw2[(co2*60+ci2)*27 + t]) : (short)0;
  }
}

// ---------------- bias table -> packed bf16 pairs ----------------
__global__ __launch_bounds__(256) void bias_prep(const int* __restrict__ rpi,
    const float* __restrict__ rpb, short* __restrict__ biasB){
  int i = blockIdx.x*256 + threadIdx.x;   // q*512+k
  int q = i>>9, k = i&511;
  int kt = k>>5, kin = k&31;
  int j = kt*32 + ((kin<16) ? 2*kin : 2*(kin-16)+1);
  int idx = rpi[i];
  #pragma unroll
  for(int h=0;h<6;h++)
    biasB[((size_t)h*512 + q)*512 + j] = f2bf(rpb[idx*6+h]);
}

// ---------------- layernorm -> bf16 (padded xnp or compact 192) ----------------
template<int PADDED>
__global__ __launch_bounds__(256) void ln_bf16(const float* __restrict__ x,
    const float* __restrict__ g, const float* __restrict__ b, short* __restrict__ outb){
  int token = blockIdx.x*4 + (threadIdx.x>>6);
  int lane  = threadIdx.x & 63;
  const float* row = x + (size_t)token*CCH;
  float v0 = row[lane], v1 = row[lane+64];
  float v2 = (lane<52) ? row[lane+128] : 0.f;
  float s = v0+v1+v2;
  #pragma unroll
  for(int m=1;m<64;m<<=1) s += __shfl_xor(s, m, 64);
  float mean = s*(1.f/180.f);
  float d0=v0-mean, d1=v1-mean, d2=(lane<52)?(v2-mean):0.f;
  float sq = d0*d0+d1*d1+d2*d2;
  #pragma unroll
  for(int m=1;m<64;m<<=1) sq += __shfl_xor(sq, m, 64);
  float rstd = rsqrtf(sq*(1.f/180.f)+1e-5f);
  size_t orow;
  if(PADDED){
    int bb=token>>14, d=(token>>10)&15, h=(token>>5)&31, w=token&31;
    orow = ((size_t)((bb*18+d+1)*34 + h+1)*34 + w+1)*192;
  } else {
    orow = (size_t)token*192;
  }
  short* o = outb + orow;
  o[lane]    = f2bf(d0*rstd*g[lane]    + b[lane]);
  o[lane+64] = f2bf(d1*rstd*g[lane+64] + b[lane+64]);
  o[lane+128]= (lane<52) ? f2bf(d2*rstd*g[lane+128] + b[lane+128]) : (short)0;
}

// ---------------- conv1: 192->64, M=64, tap-split waves, single stage ----------------
// 4 waves each compute partial M64xCO64 over ~7 taps; LDS reduce at end.
__global__ __launch_bounds__(256,1) void conv1_mfma(const short* __restrict__ in,
    const short* __restrict__ wb, const float* __restrict__ cbias, short* __restrict__ y1p){
  __shared__ short lds[78336];   // 3 planes x 4 rows x 34 w x 192 ci (156.7 KB)
  int bid = blockIdx.x;
  int xcd = bid&7, idx = bid>>3;
  int b = idx>>5, dd=(idx>>4)&1, hg=idx&15;
  int d = xcd*2+dd;
  int h0 = hg*2;
  int tid=threadIdx.x, l=tid&63, l15=l&15, g=l>>4, wid=tid>>6;
  int soff[13];
  #pragma unroll
  for(int it=0; it<13; it++){
    int t = it*256 + tid;
    int rr = t/24, s = t - rr*24;
    soff[it] = rr*192 + (((s&~7)|((s&7)^(rr&7)))<<3);
  }
  // ---- stage all 3 kd planes, one barrier ----
  #pragma unroll
  for(int kd=0; kd<3; kd++){
    const short* S = in + (((size_t)(b*18+d+kd)*34 + h0)*34)*192;
    short* L = lds + kd*26112;
    #pragma unroll
    for(int it=0; it<13; it++){
      if(it<12 || tid<192)
        gload16(S + soff[it], L + (size_t)(it*256+wid*64)*8);
    }
  }
  asm volatile("s_waitcnt vmcnt(0)" ::: "memory");
  __builtin_amdgcn_s_barrier();
  f32x4 acc[4][4];
  #pragma unroll
  for(int i=0;i<4;i++)
    #pragma unroll
    for(int j=0;j<4;j++) acc[i][j]=(f32x4){0.f,0.f,0.f,0.f};
  for(int ti = wid; ti < 27; ti += 4){
    int kd = ti/9; int r2 = ti - kd*9; int kh = r2/3; int kw = r2 - kh*3;
    const short* wt = wb + (size_t)ti*12288;
    int Rb = kd*136 + kh*34 + kw;
    #pragma unroll
    for(int ks=0; ks<6; ks++){
      int s = ks*4+g;
      short8 bv[4];
      #pragma unroll
      for(int nj=0;nj<4;nj++)
        bv[nj] = *(const short8*)&wt[(size_t)(nj*16+l15)*192 + ks*32 + g*8];
      #pragma unroll
      for(int mi=0;mi<4;mi++){
        int R = Rb + (mi>>1)*34 + (mi&1)*16 + l15;
        short8 av = *(const short8*)&lds[R*192 + (((s&~7)|((s&7)^(R&7)))<<3)];
        #pragma unroll
        for(int nj=0;nj<4;nj++)
          acc[mi][nj] = __builtin_amdgcn_mfma_f32_16x16x32_bf16(av, bv[nj], acc[mi][nj],0,0,0);
      }
    }
  }
  __syncthreads();
  float* scrf = (float*)lds;
  #pragma unroll
  for(int i=0;i<4;i++)
    #pragma unroll
    for(int j=0;j<4;j++)
      #pragma unroll
      for(int reg=0;reg<4;reg++)
        scrf[wid*4160 + (i*16+g*4+reg)*65 + j*16+l15] = acc[i][j][reg];
  __syncthreads();
  size_t prow0 = ((size_t)(b*18+d+1)*34 + h0+1)*34 + 1;
  for(int idx2=tid; idx2<4096; idx2+=256){
    int r = idx2>>6, co = idx2&63;
    float v = scrf[r*65+co] + scrf[4160 + r*65+co]
            + scrf[8320 + r*65+co] + scrf[12480 + r*65+co];
    float bb = (co<60)? cbias[co] : 0.f;
    int hr = r>>5, w = r&31;
    y1p[(prow0 + hr*34 + w)*64 + co] = f2bf(geluf(v+bb));
  }
}

// ---------------- conv2: 64->192, M=64, co-split waves, single stage, fused pool ----
__global__ __launch_bounds__(256) void conv2_mfma(const short* __restrict__ in,
    const short* __restrict__ wb, const float* __restrict__ cbias,
    short* __restrict__ y2b, float* __restrict__ pooled){
  __shared__ short lds[26112];   // 3 planes x 4 rows x 34 w x 64 ci
  int bid = blockIdx.x;
  int xcd = bid&7, idx = bid>>3;
  int b = idx>>5, dd=(idx>>4)&1, hg=idx&15;
  int d = xcd*2+dd;
  int h0 = hg*2;
  int tid=threadIdx.x, l=tid&63, l15=l&15, g=l>>4, wid=tid>>6;
  int soff[5];
  #pragma unroll
  for(int it=0; it<5; it++){
    int t = it*256 + tid;
    int rr = t>>3, s = t&7;
    soff[it] = rr*64 + ((s^(rr&7))<<3);
  }
  #pragma unroll
  for(int kd=0; kd<3; kd++){
    const short* S = in + (((size_t)(b*18+d+kd)*34 + h0)*34)*64;
    short* L = lds + kd*8704;
    #pragma unroll
    for(int it=0; it<5; it++){
      if(it<4 || tid<64)
        gload16(S + soff[it], L + (size_t)(it*256+wid*64)*8);
    }
  }
  asm volatile("s_waitcnt vmcnt(0)" ::: "memory");
  __builtin_amdgcn_s_barrier();
  f32x4 acc[4][3];
  #pragma unroll
  for(int mi=0;mi<4;mi++)
    #pragma unroll
    for(int nj=0;nj<3;nj++) acc[mi][nj]=(f32x4){0.f,0.f,0.f,0.f};
  for(int ti=0; ti<27; ti++){
    int kd = ti/9; int r2 = ti - kd*9; int kh = r2/3; int kw = r2 - kh*3;
    const short* wt = wb + (size_t)ti*12288;
    int Rb = kd*136 + kh*34 + kw;
    #pragma unroll
    for(int ks=0; ks<2; ks++){
      int s = ks*4+g;
      short8 bv[3];
      #pragma unroll
      for(int nj=0;nj<3;nj++)
        bv[nj] = *(const short8*)&wt[(size_t)(wid*48+nj*16+l15)*64 + ks*32 + g*8];
      #pragma unroll
      for(int mi=0;mi<4;mi++){
        int R = Rb + (mi>>1)*34 + (mi&1)*16 + l15;
        short8 av = *(const short8*)&lds[R*64 + ((s^(R&7))<<3)];
        #pragma unroll
        for(int nj=0;nj<3;nj++)
          acc[mi][nj] = __builtin_amdgcn_mfma_f32_16x16x32_bf16(av, bv[nj], acc[mi][nj],0,0,0);
      }
    }
  }
  size_t token0 = ((size_t)(b*16+d)*32 + h0)*32;
  #pragma unroll
  for(int nj=0;nj<3;nj++){
    int co = wid*48 + nj*16 + l15;
    float ps = 0.f;
    #pragma unroll
    for(int mi=0;mi<4;mi++)
      #pragma unroll
      for(int reg=0;reg<4;reg++) ps += acc[mi][nj][reg];
    ps += __shfl_xor(ps,16,64);
    ps += __shfl_xor(ps,32,64);
    if(co<180){
      float bb = cbias[co];
      #pragma unroll
      for(int mi=0;mi<4;mi++)
        #pragma unroll
        for(int reg=0;reg<4;reg++){
          int r = mi*16 + g*4 + reg;
          int hr = r>>5, w = r&31;
          y2b[(token0 + hr*32 + w)*192 + co] = f2bf(acc[mi][nj][reg] + bb);
        }
      if(l<16) atomicAdd(&pooled[b*180 + co], ps);
    }
  }
}

// ---------------- channel attention (reads raw pooled sums) ----------------
__global__ void chattn_kernel(const float* __restrict__ pooled, const float* __restrict__ cb2,
    const float* __restrict__ caw1, const float* __restrict__ cab1,
    const float* __restrict__ caw2, const float* __restrict__ cab2,
    float* __restrict__ amask){
  __shared__ float hid[2][6];
  int t = threadIdx.x;
  if(t<12){
    int b = t/6, qh = t - b*6;
    float s = cab1[qh];
    for(int c=0;c<180;c++){
      float pv = pooled[b*180+c]*(1.f/16384.f) + cb2[c];
      s += pv*caw1[qh*180+c];
    }
    hid[b][qh] = fmaxf(s, 0.f);
  }
  __syncthreads();
  for(int i=t;i<360;i+=64){
    int b = i/180, c = i - b*180;
    float s = cab2[c];
    #pragma unroll
    for(int qh=0;qh<6;qh++) s += hid[b][qh]*caw2[c*6+qh];
    amask[i] = 1.f/(1.f+__expf(-s));
  }
}

// ---------------- window-token <-> row mappings ----------------
__device__ __forceinline__ void wtok_decomp(int t, int& b, int& dd, int& hh, int& ww){
  int win = t >> 9, n = t & 511;
  int sb = win >> 2, wi = win & 3;
  int wh = wi >> 1, wwi = wi & 1;
  b = sb >> 3; int r = sb & 7;
  int id = r >> 2, ih = (r>>1)&1, iw = r&1;
  int td = n >> 6, th = (n>>3)&7, tw = n & 7;
  dd = td*2 + id;
  hh = (wh*8+th)*2 + ih;
  ww = (wwi*8+tw)*2 + iw;
}
__device__ __forceinline__ int wtok_to_row(int t){
  int b,dd,hh,ww; wtok_decomp(t,b,dd,hh,ww);
  return b*16384 + (dd*32+hh)*32 + ww;
}
__device__ __forceinline__ int wtok_to_prow(int t){
  int b,dd,hh,ww; wtok_decomp(t,b,dd,hh,ww);
  return ((b*18+dd+1)*34 + hh+1)*34 + ww + 1;
}

// ---------------- bf16 MFMA GEMM 128x128, gload_lds dbuf pipeline ----------------
template<int MODE, int NOUT, int KTOT>
__global__ __launch_bounds__(256) void mgemm(const short* __restrict__ A,
    const short* __restrict__ Wb, const float* __restrict__ bias, void* __restrict__ outv,
    const float* __restrict__ e0, const float* __restrict__ e1,
    const float* __restrict__ e2){
  __shared__ short As[2][8192];
  __shared__ short Bs[2][8192];
  __shared__ int rowmap[128];
  int lin = blockIdx.y*gridDim.x + blockIdx.x;
  int xcd = lin&7, k = lin>>3;
  int bm = xcd*32 + (k & 31);
  int bn = k >> 5;
  int tid = threadIdx.x;
  int l = tid&63, l15=l&15, g=l>>4, wid=tid>>6;
  int wm = wid>>1, wn = wid&1;
  constexpr int RS = (MODE==3)?768:192;
  if(MODE==0 || MODE==1){
    if(tid<128) rowmap[tid] = (MODE==0) ? wtok_to_prow(bm*128+tid) : wtok_to_row(bm*128+tid);
  }
  __syncthreads();
  f32x4 acc[4][4];
  #pragma unroll
  for(int i=0;i<4;i++)
    #pragma unroll
    for(int j=0;j<4;j++) acc[i][j] = (f32x4){0.f,0.f,0.f,0.f};

  constexpr int NCH = KTOT/64;
  auto STAGE = [&](int ch, int p){
    int k0 = ch*64;
    #pragma unroll
    for(int it=0; it<4; it++){
      int i = it*256 + wid*64 + l;
      int r = i>>3, sl = (i&7) ^ (r&7);
      size_t row = (size_t)((MODE==0||MODE==1) ? rowmap[r] : bm*128+r);
      gload16(A + row*RS + k0 + sl*8, &As[p][(size_t)(it*256+wid*64)*8]);
    }
    #pragma unroll
    for(int it=0; it<4; it++){
      int i = it*256 + wid*64 + l;
      int c = i>>3, sl = (i&7) ^ (c&7);
      gload16(Wb + (size_t)(bn*128+c)*KTOT + k0 + sl*8, &Bs[p][(size_t)(it*256+wid*64)*8]);
    }
  };
  STAGE(0,0);
  for(int ch=0; ch<NCH; ch++){
    if(ch+1<NCH){
      STAGE(ch+1,(ch+1)&1);
      asm volatile("s_waitcnt vmcnt(8)" ::: "memory");
    } else {
      asm volatile("s_waitcnt vmcnt(0)" ::: "memory");
    }
    __builtin_amdgcn_s_barrier();
    const short* as = As[ch&1];
    const short* bs = Bs[ch&1];
    #pragma unroll
    for(int ks=0; ks<2; ks++){
      short8 av[4], bv[4];
      #pragma unroll
      for(int i=0;i<4;i++){
        int r = wm*64 + i*16 + l15;
        av[i] = *(const short8*)&as[r*64 + (((ks*4+g) ^ (r&7))<<3)];
      }
      #pragma unroll
      for(int j=0;j<4;j++){
        int c = wn*64 + j*16 + l15;
        bv[j] = *(const short8*)&bs[c*64 + (((ks*4+g) ^ (c&7))<<3)];
      }
      #pragma unroll
      for(int i=0;i<4;i++)
        #pragma unroll
        for(int j=0;j<4;j++)
          acc[i][j] = __builtin_amdgcn_mfma_f32_16x16x32_bf16(av[i], bv[j], acc[i][j],0,0,0);
    }
    asm volatile("" ::: "memory");
    __builtin_amdgcn_s_barrier();
  }
  // ---- epilogue ----
  #pragma unroll
  for(int i=0;i<4;i++){
    int rloc0 = wm*64 + i*16 + g*4;
    #pragma unroll
    for(int j=0;j<4;j++){
      int o = bn*128 + wn*64 + j*16 + l15;
      if(MODE!=2 && o>=NOUT) continue;
      float bb = (o<NOUT) ? bias[o] : 0.f;
      #pragma unroll
      for(int reg=0; reg<4; reg++){
        int rl = rloc0 + reg;
        int trow = bm*128 + rl;
        float v = acc[i][j][reg] + bb;
        if(MODE==0){
          int which = o/180; int chn = o - which*180;
          int head = chn/30; int hd = chn - head*30;
          int win = trow>>9, n = trow&511;
          if(which==0){
            size_t sidx = ((size_t)(win*6+head)*512 + n)*32;
            ((short*)outv)[sidx + hd] = f2bf(v*SCALE_Q);
            if(hd==0) *(int*)&((short*)outv)[sidx + 30] = 0;
          } else if(which==1){
            size_t sidx = 6291456 + ((size_t)(win*6+head)*512 + n)*32;
            ((short*)outv)[sidx + hd] = f2bf(v);
            if(hd==0) *(int*)&((short*)outv)[sidx + 30] = 0;
          } else {
            ((short*)outv)[12582912 + ((size_t)(win*6+head)*32 + hd)*512 + n] = f2bf(v);
          }
        } else if(MODE==1){
          int grow = rowmap[rl];
          float conv = bf2f(((const short*)e1)[(size_t)grow*192 + o]);
          float am   = e2[(grow>>14)*180 + o];
          ((float*)outv)[(size_t)grow*180+o] = v + e0[(size_t)grow*180+o] + conv*am*0.01f;
        } else if(MODE==2){
          ((short*)outv)[(size_t)trow*768+o] = (o<720) ? f2bf(geluf(v)) : (short)0;
        } else {
          ((float*)outv)[(size_t)trow*180+o] = v + e0[(size_t)trow*180+o];
        }
      }
    }
  }
}

// ---------------- window attention: fixed-max softmax, bf16 MFMA ----------------
__global__ __launch_bounds__(256) void attn_mfma(const short* __restrict__ qkvb,
    const short* __restrict__ biasB, short* __restrict__ attnb){
  __shared__ short Ks[1024];
  __shared__ short Vt[1024];
  __shared__ short Ps[4096];
  int bid = blockIdx.x;
  int j0 = bid>>3;
  int grp = (bid&7)*48 + (j0>>2);
  int qt = j0&3;
  int win = grp/6, head = grp - (grp/6)*6;
  int tid = threadIdx.x, w = tid>>6, l = tid&63, l15 = l&15, g = l>>4;
  const short* qp = qkvb + (size_t)(win*6+head)*16384;
  const short* kp = qp + 6291456;
  const short* vp = qkvb + 12582912 + (size_t)(win*6+head)*16384;
  int qbase = qt*128 + w*32;
  short8 aq0 = *(const short8*)&qp[(size_t)(qbase + l15)*32 + g*8];
  short8 aq1 = *(const short8*)&qp[(size_t)(qbase + 16 + l15)*32 + g*8];
  const short* bB = biasB + ((size_t)head*512 + qbase)*512;
  f32x4 acc[2][2];
  float lsum[2][4];
  #pragma unroll
  for(int a=0;a<2;a++){
    #pragma unroll
    for(int r=0;r<4;r++) lsum[a][r]=0.f;
    #pragma unroll
    for(int b2=0;b2<2;b2++) acc[a][b2]=(f32x4){0.f,0.f,0.f,0.f};
  }
  int pbase = w*1024;
  int rrA = l15>>1, sA = ((l15&1)<<2)|g;
  int offT0 = rrA*64 + ((sA ^ (rrA&7))<<3);
  int rrB = 8+rrA;
  int offT1 = rrB*64 + ((sA ^ (rrB&7))<<3);
  int strr = (tid&127)>>3, sts = tid&7;
  int stoff = strr*64 + ((sts ^ (strr&7))<<3);
  int sttok = strr*2 + (sts>>2), sthd8 = (sts&3)*8;

  for(int kt=0; kt<16; kt++){
    if(tid<128){
      short8 v = *(const short8*)&kp[(size_t)(kt*32+sttok)*32 + sthd8];
      *(short8*)&Ks[stoff] = v;
    } else {
      short8 v = *(const short8*)&vp[(size_t)sttok*512 + kt*32 + sthd8];
      *(short8*)&Vt[stoff] = v;
    }
    unsigned ub[2][4];
    #pragma unroll
    for(int mf=0; mf<2; mf++)
      #pragma unroll
      for(int reg=0; reg<4; reg++)
        ub[mf][reg] = *(const unsigned*)&bB[(size_t)(mf*16+g*4+reg)*512 + kt*32 + 2*l15];
    __syncthreads();
    short8 bk0 = *(const short8*)&Ks[offT0];
    short8 bk1 = *(const short8*)&Ks[offT1];
    f32x4 z = (f32x4){0.f,0.f,0.f,0.f};
    f32x4 s00 = __builtin_amdgcn_mfma_f32_16x16x32_bf16(aq0, bk0, z,0,0,0);
    f32x4 s01 = __builtin_amdgcn_mfma_f32_16x16x32_bf16(aq0, bk1, z,0,0,0);
    f32x4 s10 = __builtin_amdgcn_mfma_f32_16x16x32_bf16(aq1, bk0, z,0,0,0);
    f32x4 s11 = __builtin_amdgcn_mfma_f32_16x16x32_bf16(aq1, bk1, z,0,0,0);
    #pragma unroll
    for(int mf=0; mf<2; mf++){
      #pragma unroll
      for(int reg=0; reg<4; reg++){
        float b0 = __uint_as_float(ub[mf][reg]<<16);
        float b1 = __uint_as_float(ub[mf][reg]&0xFFFF0000u);
        float sv0 = (mf==0)? s00[reg] : s10[reg];
        float sv1 = (mf==0)? s01[reg] : s11[reg];
        float p0 = __expf(fminf(sv0 + b0, 60.f));
        float p1 = __expf(fminf(sv1 + b1, 60.f));
        lsum[mf][reg] += p0 + p1;
        int q = mf*16 + g*4 + reg;
        int rr = q>>1;
        int s0 = ((q&1)<<2) | (l15>>3);
        int s1 = s0 + 2;
        Ps[pbase + rr*64 + ((s0 ^ (rr&7))<<3) + (l15&7)] = f2bf(p0);
        Ps[pbase + rr*64 + ((s1 ^ (rr&7))<<3) + (l15&7)] = f2bf(p1);
      }
    }
    short8 ap0 = *(const short8*)&Ps[pbase + offT0];
    short8 ap1 = *(const short8*)&Ps[pbase + offT1];
    short8 bv0 = *(const short8*)&Vt[offT0];
    short8 bv1 = *(const short8*)&Vt[offT1];
    acc[0][0] = __builtin_amdgcn_mfma_f32_16x16x32_bf16(ap0, bv0, acc[0][0],0,0,0);
    acc[0][1] = __builtin_amdgcn_mfma_f32_16x16x32_bf16(ap0, bv1, acc[0][1],0,0,0);
    acc[1][0] = __builtin_amdgcn_mfma_f32_16x16x32_bf16(ap1, bv0, acc[1][0],0,0,0);
    acc[1][1] = __builtin_amdgcn_mfma_f32_16x16x32_bf16(ap1, bv1, acc[1][1],0,0,0);
    __syncthreads();
  }
  int token = win*512 + qbase;
  #pragma unroll
  for(int mf=0; mf<2; mf++)
  #pragma unroll
  for(int reg=0; reg<4; reg++){
    float lv = lsum[mf][reg];
    lv += __shfl_xor(lv,1,64); lv += __shfl_xor(lv,2,64);
    lv += __shfl_xor(lv,4,64); lv += __shfl_xor(lv,8,64);
    float inv = 1.f/lv;
    int qg = token + mf*16 + g*4 + reg;
    short* orow = attnb + (size_t)qg*192 + head*30;
    if(l15<30) orow[l15] = f2bf(acc[mf][0][reg]*inv);
    if(l15<14) orow[16+l15] = f2bf(acc[mf][1][reg]*inv);
    if(head==5 && l15<12) attnb[(size_t)qg*192 + 180 + l15] = 0;
  }
}

// ---------------- launcher ----------------
extern "C" void kernel_launch(void* const* d_in, const int* in_sizes, int n_in,
                              void* d_out, int out_size, void* d_ws, size_t ws_size,
                              hipStream_t stream){
  const float* x      = (const float*)d_in[0];
  const int*   rpi    = (const int*)  d_in[4];
  const float* g1     = (const float*)d_in[7];
  const float* b1     = (const float*)d_in[8];
  const float* qkv_w  = (const float*)d_in[9];
  const float* qkv_b  = (const float*)d_in[10];
  const float* rpb    = (const float*)d_in[11];
  const float* proj_w = (const float*)d_in[12];
  const float* proj_b = (const float*)d_in[13];
  const float* cw1    = (const float*)d_in[14];
  const float* cb1    = (const float*)d_in[15];
  const float* cw2    = (const float*)d_in[16];
  const float* cb2    = (const float*)d_in[17];
  const float* caw1   = (const float*)d_in[18];
  const float* cab1   = (const float*)d_in[19];
  const float* caw2   = (const float*)d_in[20];
  const float* cab2   = (const float*)d_in[21];
  const float* g2     = (const float*)d_in[22];
  const float* b2     = (const float*)d_in[23];
  const float* fc1_w  = (const float*)d_in[24];
  const float* fc1_b  = (const float*)d_in[25];
  const float* fc2_w  = (const float*)d_in[26];
  const float* fc2_b  = (const float*)d_in[27];
  float* ws = (float*)d_ws;
  float* fout = (float*)d_out;
  short* attnb = (short*)(ws + OFF_ATTNB);
  short* xnp   = (short*)(ws + OFF_XNP);
  short* y1p   = (short*)(ws + OFF_Y1P);
  short* qkvb  = (short*)(ws + OFF_QKVB);
  short* hid   = (short*)(ws + OFF_HID);
  short* y2b   = (short*)(ws + OFF_Y2B);
  short* x2n   = (short*)(ws + OFF_X2N);
  short* biasB = (short*)(ws + OFF_BIASB);
  short* wq    = (short*)(ws + OFF_WQKV);
  short* wp    = (short*)(ws + OFF_WPROJ);
  short* w1    = (short*)(ws + OFF_WFC1);
  short* w2    = (short*)(ws + OFF_WFC2);
  short* wb1   = (short*)(ws + OFF_WB1);
  short* wb2   = (short*)(ws + OFF_WB2);

  hipMemsetAsync(xnp, 0, (size_t)7990272*2, stream);
  hipMemsetAsync(y1p, 0, (size_t)2663424*2, stream);
  hipMemsetAsync(ws+OFF_POOL, 0, 360*4, stream);
  prep_wb<<<2016,256,0,stream>>>(qkv_w, proj_w, fc1_w, fc2_w, wq, wp, w1, w2);
  prep_wbc<<<1296,256,0,stream>>>(cw1, cw2, wb1, wb2);
  bias_prep<<<1024,256,0,stream>>>(rpi, rpb, biasB);
  ln_bf16<1><<<8192,256,0,stream>>>(x, g1, b1, xnp);
  conv1_mfma<<<512,256,0,stream>>>(xnp, wb1, cb1, y1p);
  conv2_mfma<<<512,256,0,stream>>>(y1p, wb2, cb2, y2b, ws+OFF_POOL);
  chattn_kernel<<<1,64,0,stream>>>(ws+OFF_POOL, cb2, caw1, cab1, caw2, cab2, ws+OFF_AM);
  mgemm<0,540,192><<<dim3(256,5),256,0,stream>>>(
      xnp, wq, qkv_b, qkvb, nullptr, nullptr, nullptr);
  attn_mfma<<<1536,256,0,stream>>>(qkvb, biasB, attnb);
  mgemm<1,180,192><<<dim3(256,2),256,0,stream>>>(
      attnb, wp, proj_b, ws+OFF_X2, x, (const float*)y2b, ws+OFF_AM);
  ln_bf16<0><<<8192,256,0,stream>>>(ws+OFF_X2, g2, b2, x2n);
  mgemm<2,720,192><<<dim3(256,6),256,0,stream>>>(
      x2n, w1, fc1_b, hid, nullptr, nullptr, nullptr);
  mgemm<3,180,768><<<dim3(256,2),256,0,stream>>>(
      hid, w2, fc2_b, fout, ws+OFF_X2, nullptr, nullptr);
}